// Round 1
// baseline (712.897 us; speedup 1.0000x reference)
//
#include <hip/hip_runtime.h>
#include <hip/hip_bf16.h>

#define H    2048
#define NI   1408
#define NE   8
#define NTOK 2048
#define NIS  2816

typedef __bf16 bf16x8 __attribute__((ext_vector_type(8)));
typedef float  f32x4  __attribute__((ext_vector_type(4)));

#define ASYNC16(gp, lp) __builtin_amdgcn_global_load_lds( \
    (const __attribute__((address_space(1))) void*)(gp),  \
    (__attribute__((address_space(3))) void*)(lp), 16, 0, 0)

#define MFMA16 __builtin_amdgcn_mfma_f32_16x16x32_bf16

// ---------------------------------------------------------------------------
// Elementwise fp32 -> bf16 (x), 8 elems/thread
// ---------------------------------------------------------------------------
__global__ __launch_bounds__(256)
void cvt_kernel(const float* __restrict__ in, __bf16* __restrict__ out)
{
    size_t i = ((size_t)blockIdx.x * 256 + threadIdx.x) * 8;
    float4 v0 = *(const float4*)(in + i);
    float4 v1 = *(const float4*)(in + i + 4);
    union { __bf16 b[8]; uint4 u; } p;
    p.b[0] = (__bf16)v0.x; p.b[1] = (__bf16)v0.y;
    p.b[2] = (__bf16)v0.z; p.b[3] = (__bf16)v0.w;
    p.b[4] = (__bf16)v1.x; p.b[5] = (__bf16)v1.y;
    p.b[6] = (__bf16)v1.z; p.b[7] = (__bf16)v1.w;
    *(uint4*)(out + i) = p.u;
}

// ---------------------------------------------------------------------------
// Transpose-convert: in fp32 [K][N] (batched by z) -> out bf16 [N][K]
// ---------------------------------------------------------------------------
__global__ __launch_bounds__(256)
void cvt_t_kernel(const float* __restrict__ in, __bf16* __restrict__ out,
                  int K, int N)
{
    const size_t zoff = (size_t)blockIdx.z * K * N;
    in  += zoff;
    out += zoff;
    const int n0 = blockIdx.x * 64;
    const int k0 = blockIdx.y * 64;
    __shared__ __bf16 tile[64][72];
    const int t = threadIdx.x;
    const int tr  = t >> 4;
    const int tc4 = (t & 15) * 4;
#pragma unroll
    for (int i = 0; i < 4; ++i) {
        int k = i * 16 + tr;
        float4 v = *(const float4*)(in + (size_t)(k0 + k) * N + n0 + tc4);
        tile[k][tc4 + 0] = (__bf16)v.x;
        tile[k][tc4 + 1] = (__bf16)v.y;
        tile[k][tc4 + 2] = (__bf16)v.z;
        tile[k][tc4 + 3] = (__bf16)v.w;
    }
    __syncthreads();
    const int n = t >> 2, q = t & 3;
#pragma unroll
    for (int hh = 0; hh < 2; ++hh) {
        int qq = q + hh * 4;
        union { __bf16 b[8]; uint4 u; } pk;
#pragma unroll
        for (int j = 0; j < 8; ++j) pk.b[j] = tile[qq * 8 + j][n];
        *(uint4*)(out + (size_t)(n0 + n) * K + k0 + qq * 8) = pk.u;
    }
}

// ---------------------------------------------------------------------------
// Gate: fp32 logits -> softmax -> top2 -> per-expert pair lists
// ---------------------------------------------------------------------------
__global__ __launch_bounds__(256)
void gate_kernel(const float* __restrict__ x, const float* __restrict__ gw,
                 float* __restrict__ topw, int* __restrict__ pairs,
                 int* __restrict__ cnt)
{
    int tok  = blockIdx.x * 4 + (threadIdx.x >> 6);
    int lane = threadIdx.x & 63;
    float acc[NE];
#pragma unroll
    for (int e = 0; e < NE; ++e) acc[e] = 0.f;
    const float* xr = x + (size_t)tok * H;
    for (int h = lane; h < H; h += 64) {
        float xv = xr[h];
#pragma unroll
        for (int e = 0; e < NE; ++e) acc[e] += xv * gw[e * H + h];
    }
#pragma unroll
    for (int e = 0; e < NE; ++e) {
        float v = acc[e];
        for (int off = 32; off; off >>= 1) v += __shfl_xor(v, off);
        acc[e] = v;
    }
    if (lane == 0) {
        float mx = acc[0];
#pragma unroll
        for (int e = 1; e < NE; ++e) mx = fmaxf(mx, acc[e]);
        float p[NE]; float s = 0.f;
#pragma unroll
        for (int e = 0; e < NE; ++e) { p[e] = __expf(acc[e] - mx); s += p[e]; }
        float inv = 1.f / s;
        int e1 = 0;
#pragma unroll
        for (int e = 1; e < NE; ++e) if (acc[e] > acc[e1]) e1 = e;
        int e2 = -1;
#pragma unroll
        for (int e = 0; e < NE; ++e) {
            if (e == e1) continue;
            if (e2 < 0 || acc[e] > acc[e2]) e2 = e;
        }
        topw[tok * 2 + 0] = p[e1] * inv;
        topw[tok * 2 + 1] = p[e2] * inv;
        int pos1 = atomicAdd(&cnt[e1], 1);
        pairs[e1 * NTOK + pos1] = tok * 2 + 0;
        int pos2 = atomicAdd(&cnt[e2], 1);
        pairs[e2 * NTOK + pos2] = tok * 2 + 1;
    }
}

// ---------------------------------------------------------------------------
// Merged GU GEMM, phased-pipeline version (T2+T3+T4+T5):
//   z<NE -> routed expert z (gathered rows, out h_rt[pid]); z==NE -> shared.
// C = silu(A@Bg^T) * (A@Bu^T), A bf16 [.][H], B^T bf16 [n][H].
// BM=256, BN=128, BK=32, 512 thr / 8 waves (4Mx2N), 3-deep LDS pipeline,
// counted vmcnt(4) (never 0 in steady state), raw s_barrier (no drain),
// XOR chunk-swizzle both-sides (pre-swizzled global src, swizzled ds_read).
// ---------------------------------------------------------------------------
__global__ __launch_bounds__(512, 2)
void gu_kernel(const __bf16* __restrict__ xb,
               const __bf16* __restrict__ wgT, const __bf16* __restrict__ wuT,
               const __bf16* __restrict__ swgT, const __bf16* __restrict__ swuT,
               __bf16* __restrict__ h_sh, __bf16* __restrict__ h_rt,
               const int* __restrict__ pairs, const int* __restrict__ cnt)
{
    const int t = threadIdx.x, lane = t & 63;
    const int wid = t >> 6;        // 0..7
    const int wm = wid >> 1;       // 0..3  (64-row slice)
    const int wn = wid & 1;        // 0..1  (64-col slice)
    const int e = blockIdx.z;
    const bool routed = (e < NE);
    const int m0 = blockIdx.y * 256, n0 = blockIdx.x * 128;

    int count = NTOK;
    const __bf16 *Bg, *Bu;
    __bf16* outp;
    int ldO;
    if (routed) {
        if (n0 >= NI) return;
        count = cnt[e];
        if (m0 >= count) return;
        Bg = wgT + (size_t)e * NI * H;
        Bu = wuT + (size_t)e * NI * H;
        outp = h_rt; ldO = NI;
    } else {
        Bg = swgT; Bu = swuT; outp = h_sh; ldO = NIS;
    }

    // 3-deep buffers: A 3x(256x32), Bg/Bu 3x(128x32)  => 97 KB
    __shared__ __align__(16) __bf16 At [3 * 256 * 32];
    __shared__ __align__(16) __bf16 Btg[3 * 128 * 32];
    __shared__ __align__(16) __bf16 Btu[3 * 128 * 32];
    __shared__ int tile_pid[256];

    if (t < 256) {
        int j = m0 + t;
        tile_pid[t] = routed ? ((j < count) ? pairs[e * NTOK + j] : -1) : j;
    }
    __syncthreads();

    // ---- staging setup: thread t owns 16B chunk (row = t>>2, c_lds = t&3)
    // LDS(row, c_lds) must hold global chunk c_lds ^ swz(row), swz(r)=(r>>1)&3
    const int sr = t >> 2;                    // 0..127 (row within sweep)
    const int cg = (t & 3) ^ ((t >> 3) & 3);  // pre-swizzled global chunk
    size_t ar0, ar1;
    if (routed) {
        int p0 = tile_pid[sr];        if (p0 < 0) p0 = 0;
        int p1 = tile_pid[128 + sr];  if (p1 < 0) p1 = 0;
        ar0 = (size_t)(p0 >> 1); ar1 = (size_t)(p1 >> 1);
    } else {
        ar0 = (size_t)(m0 + sr); ar1 = (size_t)(m0 + 128 + sr);
    }
    const __bf16* gA0 = xb + ar0 * H + cg * 8;
    const __bf16* gA1 = xb + ar1 * H + cg * 8;
    const __bf16* gBg = Bg + (size_t)(n0 + sr) * H + cg * 8;
    const __bf16* gBu = Bu + (size_t)(n0 + sr) * H + cg * 8;
    __bf16* lA0 = At  + t * 8;          // + buf*8192
    __bf16* lA1 = At  + 4096 + t * 8;   // + buf*8192
    __bf16* lBg = Btg + t * 8;          // + buf*4096
    __bf16* lBu = Btu + t * 8;          // + buf*4096

    // ---- fragment read offsets (chunk-swizzled; per-lane constant)
    const int fr  = lane & 15;
    const int cr8 = (((lane >> 4) ^ ((fr >> 1) & 3)) << 3);
    const int aoff = (wm * 64 + fr) * 32 + cr8;   // + mi*512 + buf*8192
    const int boff = (wn * 64 + fr) * 32 + cr8;   // + ni*512 + buf*4096

    f32x4 accg[4][4] = {};
    f32x4 accu[4][4] = {};

    // ---- prologue: stage tiles 0 (buf0) and 1 (buf1); issue order A0,A1,Bg,Bu
    ASYNC16(gA0,      lA0);         ASYNC16(gA1,      lA1);
    ASYNC16(gBg,      lBg);         ASYNC16(gBu,      lBu);
    ASYNC16(gA0 + 32, lA0 + 8192);  ASYNC16(gA1 + 32, lA1 + 8192);
    ASYNC16(gBg + 32, lBg + 4096);  ASYNC16(gBu + 32, lBu + 4096);
    asm volatile("s_waitcnt vmcnt(4)" ::: "memory");   // tile0 resident
    __builtin_amdgcn_s_barrier();

    const int NT = H / 32;   // 64
    int buf = 0;
#pragma unroll 1
    for (int tt = 0; tt < NT; ++tt) {
        const __bf16* Ab  = At  + buf * 8192;
        const __bf16* Bgb = Btg + buf * 4096;
        const __bf16* Bub = Btu + buf * 4096;
        const int nb = (buf + 2 >= 3) ? (buf - 1) : (buf + 2);  // (buf+2)%3
        const bool st = (tt + 2) < NT;
        const int ks = (tt + 2) * 32;

        // ================= phase 0: ni 0,1 =================
        bf16x8 a[4];
#pragma unroll
        for (int mi = 0; mi < 4; ++mi)
            a[mi] = *(const bf16x8*)(Ab + aoff + mi * 512);
        bf16x8 bg[2], bu[2];
#pragma unroll
        for (int ni = 0; ni < 2; ++ni) {
            bg[ni] = *(const bf16x8*)(Bgb + boff + ni * 512);
            bu[ni] = *(const bf16x8*)(Bub + boff + ni * 512);
        }
        if (st) {
            ASYNC16(gA0 + ks, lA0 + nb * 8192);
            ASYNC16(gA1 + ks, lA1 + nb * 8192);
        }
        __builtin_amdgcn_s_barrier();
        asm volatile("s_waitcnt lgkmcnt(0)" ::: "memory");
        __builtin_amdgcn_sched_barrier(0);
        __builtin_amdgcn_s_setprio(1);
#pragma unroll
        for (int ni = 0; ni < 2; ++ni)
#pragma unroll
            for (int mi = 0; mi < 4; ++mi) {
                accg[mi][ni] = MFMA16(a[mi], bg[ni], accg[mi][ni], 0, 0, 0);
                accu[mi][ni] = MFMA16(a[mi], bu[ni], accu[mi][ni], 0, 0, 0);
            }
        __builtin_amdgcn_s_setprio(0);
        __builtin_amdgcn_s_barrier();

        // ================= phase 1: ni 2,3 =================
#pragma unroll
        for (int ni = 0; ni < 2; ++ni) {
            bg[ni] = *(const bf16x8*)(Bgb + boff + (ni + 2) * 512);
            bu[ni] = *(const bf16x8*)(Bub + boff + (ni + 2) * 512);
        }
        if (st) {
            ASYNC16(gBg + ks, lBg + nb * 4096);
            ASYNC16(gBu + ks, lBu + nb * 4096);
        }
        // protect next tile's phase-0 reads: tile tt+1 fully resident.
        // steady state: 8 outstanding (tt+1's 4 oldest + tt+2's 4) -> vmcnt(4)
        if (tt < NT - 2) asm volatile("s_waitcnt vmcnt(4)" ::: "memory");
        else             asm volatile("s_waitcnt vmcnt(0)" ::: "memory");
        __builtin_amdgcn_s_barrier();
        asm volatile("s_waitcnt lgkmcnt(0)" ::: "memory");
        __builtin_amdgcn_sched_barrier(0);
        __builtin_amdgcn_s_setprio(1);
#pragma unroll
        for (int ni = 0; ni < 2; ++ni)
#pragma unroll
            for (int mi = 0; mi < 4; ++mi) {
                accg[mi][ni + 2] = MFMA16(a[mi], bg[ni], accg[mi][ni + 2], 0, 0, 0);
                accu[mi][ni + 2] = MFMA16(a[mi], bu[ni], accu[mi][ni + 2], 0, 0, 0);
            }
        __builtin_amdgcn_s_setprio(0);
        __builtin_amdgcn_s_barrier();

        buf = (buf == 2) ? 0 : (buf + 1);
    }

    // ---- epilogue: fused silu(g)*u, scatter rows via tile_pid
#pragma unroll
    for (int mi = 0; mi < 4; ++mi) {
#pragma unroll
        for (int rr = 0; rr < 4; ++rr) {
            int row = wm * 64 + mi * 16 + (lane >> 4) * 4 + rr;
            int pid = tile_pid[row];
            if (routed && pid < 0) continue;
            size_t orow = routed ? (size_t)pid : (size_t)(m0 + row);
#pragma unroll
            for (int ni = 0; ni < 4; ++ni) {
                int col = n0 + wn * 64 + ni * 16 + (lane & 15);
                float g = accg[mi][ni][rr];
                float u = accu[mi][ni][rr];
                float hv = g / (1.f + __expf(-g)) * u;
                outp[orow * (size_t)ldO + col] = (__bf16)hv;
            }
        }
    }
}

// ---------------------------------------------------------------------------
// Merged down GEMM, all-atomic epilogue into zero-initialized d_out:
//  z<NE : routed expert z: d_out[tok] += topw[pid] * (h_rt[pid] @ w_down[e])
//  z==NE: shared, K-half 0 ; z==NE+1: shared, K-half 1 (split-K, w=1)
// ---------------------------------------------------------------------------
__global__ __launch_bounds__(256, 2)
void down_kernel(const __bf16* __restrict__ h_sh, const __bf16* __restrict__ h_rt,
                 const __bf16* __restrict__ swdT, const __bf16* __restrict__ wdT,
                 float* __restrict__ out,
                 const int* __restrict__ pairs, const int* __restrict__ cnt,
                 const float* __restrict__ topw)
{
    const int t = threadIdx.x, lane = t & 63;
    const int wid = t >> 6, wm = wid >> 1, wn = wid & 1;
    const int e = blockIdx.z;
    const bool routed = (e < NE);
    const int m0 = blockIdx.y * 128, n0 = blockIdx.x * 128;

    int count = NTOK, K, lda, koff = 0;
    const __bf16 *A, *B;
    if (routed) {
        count = cnt[e];
        if (m0 >= count) return;
        A = h_rt; lda = NI; K = NI;
        B = wdT + (size_t)e * H * NI;
    } else {
        A = h_sh; lda = NIS; K = NI;          // split-K: 2816 = 2*1408
        koff = (e == NE) ? 0 : NI;
        B = swdT;
    }

    __shared__ __align__(16) __bf16 At[128 * 32], Bt[128 * 32];
    __shared__ int tile_pid[128];
    if (t < 128) {
        int j = m0 + t;
        tile_pid[t] = routed ? ((j < count) ? pairs[e * NTOK + j] : -1) : j;
    }
    __syncthreads();

    const int r = t >> 2, c = t & 3;
    size_t ar0, ar1;
    if (routed) {
        int p0 = tile_pid[r];      if (p0 < 0) p0 = 0;
        int p1 = tile_pid[r + 64]; if (p1 < 0) p1 = 0;
        ar0 = (size_t)p0; ar1 = (size_t)p1;
    } else {
        ar0 = (size_t)(m0 + r); ar1 = (size_t)(m0 + r + 64);
    }
    const __bf16* a0 = A + ar0 * lda + koff + c * 8;
    const __bf16* a1 = A + ar1 * lda + koff + c * 8;
    const __bf16* b0 = B + (size_t)(n0 + r) * lda + koff + c * 8;
    const __bf16* b1 = B + (size_t)(n0 + r + 64) * lda + koff + c * 8;
    __bf16* lA0 = At + t * 8;  __bf16* lA1 = At + (256 + t) * 8;
    __bf16* lB0 = Bt + t * 8;  __bf16* lB1 = Bt + (256 + t) * 8;

    f32x4 acc[4][4] = {};

    for (int k0 = 0; k0 < K; k0 += 32) {
        __syncthreads();
        ASYNC16(a0 + k0, lA0); ASYNC16(a1 + k0, lA1);
        ASYNC16(b0 + k0, lB0); ASYNC16(b1 + k0, lB1);
        __syncthreads();
        bf16x8 a[4];
#pragma unroll
        for (int mi = 0; mi < 4; ++mi)
            a[mi] = *(const bf16x8*)(At + (wm * 64 + mi * 16 + (lane & 15)) * 32 + (lane >> 4) * 8);
#pragma unroll
        for (int ni = 0; ni < 4; ++ni) {
            bf16x8 b = *(const bf16x8*)(Bt + (wn * 64 + ni * 16 + (lane & 15)) * 32 + (lane >> 4) * 8);
#pragma unroll
            for (int mi = 0; mi < 4; ++mi)
                acc[mi][ni] = __builtin_amdgcn_mfma_f32_16x16x32_bf16(a[mi], b, acc[mi][ni], 0, 0, 0);
        }
    }

#pragma unroll
    for (int mi = 0; mi < 4; ++mi) {
#pragma unroll
        for (int rr = 0; rr < 4; ++rr) {
            int row = wm * 64 + mi * 16 + (lane >> 4) * 4 + rr;
            int pid = tile_pid[row];
            if (routed && pid < 0) continue;
            size_t tok; float w;
            if (routed) { tok = (size_t)(pid >> 1); w = topw[pid]; }
            else        { tok = (size_t)(m0 + row); w = 1.f; }
#pragma unroll
            for (int ni = 0; ni < 4; ++ni) {
                int col = n0 + wn * 64 + ni * 16 + (lane & 15);
                atomicAdd(out + tok * H + col, w * acc[mi][ni][rr]);
            }
        }
    }
}

// ---------------------------------------------------------------------------
extern "C" void kernel_launch(void* const* d_in, const int* in_sizes, int n_in,
                              void* d_out, int out_size, void* d_ws, size_t ws_size,
                              hipStream_t stream)
{
    const float* x       = (const float*)d_in[0];
    const float* gate_w  = (const float*)d_in[1];
    const float* w_gate  = (const float*)d_in[2];
    const float* w_up    = (const float*)d_in[3];
    const float* w_down  = (const float*)d_in[4];
    const float* sw_gate = (const float*)d_in[5];
    const float* sw_up   = (const float*)d_in[6];
    const float* sw_down = (const float*)d_in[7];

    // workspace layout (158.5 MB total)
    char*   ws    = (char*)d_ws;
    float*  topw  = (float*)ws;                          // 16 KB
    int*    cnt   = (int*)(ws + 16384);                  // 128 B
    int*    pairs = (int*)(ws + 16512);                  // 64 KB
    __bf16* xb    = (__bf16*)(ws + 131072);              // 8.39 MB
    __bf16* h_sh  = (__bf16*)(ws + 8519680);             // 11.53 MB
    __bf16* h_rt  = (__bf16*)(ws + 20054016);            // 11.53 MB
    __bf16* swgT  = (__bf16*)(ws + 31588352);            // 11.53 MB
    __bf16* swuT  = (__bf16*)(ws + 43122688);            // 11.53 MB
    __bf16* swdT  = (__bf16*)(ws + 54657024);            // 11.53 MB
    __bf16* wgT   = (__bf16*)(ws + 66191360);            // 46.14 MB
    __bf16* wuT   = (__bf16*)(ws + 112328704);           // 46.14 MB
    __bf16* wdT   = wgT;  // aliased: converted AFTER gu_kernel finished with wgT

    hipMemsetAsync(cnt, 0, NE * sizeof(int), stream);
    hipMemsetAsync(d_out, 0, (size_t)NTOK * H * sizeof(float), stream);

    // fp32 -> bf16 (+transpose for weights)
    cvt_kernel<<<NTOK * H / 2048, 256, 0, stream>>>(x, xb);
    cvt_t_kernel<<<dim3(NIS / 64, H / 64, 1), 256, 0, stream>>>(sw_gate, swgT, H, NIS);
    cvt_t_kernel<<<dim3(NIS / 64, H / 64, 1), 256, 0, stream>>>(sw_up,   swuT, H, NIS);
    cvt_t_kernel<<<dim3(H / 64, NIS / 64, 1), 256, 0, stream>>>(sw_down, swdT, NIS, H);
    cvt_t_kernel<<<dim3(NI / 64, H / 64, NE), 256, 0, stream>>>(w_gate,  wgT,  H, NI);
    cvt_t_kernel<<<dim3(NI / 64, H / 64, NE), 256, 0, stream>>>(w_up,    wuT,  H, NI);

    gate_kernel<<<NTOK / 4, 256, 0, stream>>>(x, gate_w, topw, pairs, cnt);

    // merged GU (phased pipeline): z=0..7 routed, z=8 shared
    gu_kernel<<<dim3(NIS / 128, NTOK / 256, NE + 1), 512, 0, stream>>>(
        xb, wgT, wuT, swgT, swuT, h_sh, h_rt, pairs, cnt);

    // convert w_down now (aliases wgT region, safe after gu_kernel)
    cvt_t_kernel<<<dim3(H / 64, NI / 64, NE), 256, 0, stream>>>(w_down, wdT, NI, H);

    // merged down: z=0..7 routed (atomic, weighted), z=8,9 shared split-K
    down_kernel<<<dim3(H / 128, NTOK / 128, NE + 2), 256, 0, stream>>>(
        h_sh, h_rt, swdT, wdT, (float*)d_out, pairs, cnt, topw);
}